// Round 8
// baseline (127.485 us; speedup 1.0000x reference)
//
#include <hip/hip_runtime.h>
#include <math.h>

// Chamfer loss, two 16384x3 fp32 clouds. Two stream launches.
//
// Key R8 insight: gfx950 packed fp32 (v_pk_fma_f32) is throughput-NEUTRAL
// (157.3 TF peak = scalar FMA rate; R4/R6/R7 all show identical 27.7us VALU
// busy). The 21us gap to wall time was the DS pipe: 256 broadcast
// ds_read_b128/wave x 16 waves/CU x ~12cyc = 20.5us, serialized with VALU.
//
// Fix: DB points are wave-uniform -> load via the SCALAR path (s_load, SMEM
// pipe) and use them as SGPR operands of v_fma (1 SGPR/instr is legal).
// Zero LDS, zero barriers in pass 1; VALU is the only busy pipe.
// Per 2 DB points: 6 slots (||b||^2) + QPT*(6 fma + 1 min3) -> 3.9/pair,
// floor ~26.5us.
//
// Tail fix: finish = 512 blocks, 16 latency-parallel loads/thread over the
// 8.4MB mins, block partial + ticket; LAST block does the deterministic
// final sum (single writer, no same-address atomic storm — R7's 2048
// atomicAdds on out[0] serialized ~25us).

#define BLOCK  256
#define QPT    8      // queries per thread
#define SLICES 64     // pass-1 grid = 16 qchunks * 64 = 1024 blocks

__global__ __launch_bounds__(BLOCK) void chamfer_partial_min(
    const float* __restrict__ state_x, const float* __restrict__ target,
    float* __restrict__ mins, unsigned* __restrict__ counter, int N)
{
    const int tid = threadIdx.x;
    const int twoN = 2 * N;
    const int qchunk = blockIdx.x / SLICES;     // block-uniform
    const int s = blockIdx.x % SLICES;
    const int qbase = qchunk * (BLOCK * QPT);   // 2048-query chunk, 2048 | N

    if (blockIdx.x == 0 && tid == 0) *counter = 0u;   // ticket for pass 2

    const float* qcloud;
    const float* db;
    int qoff;
    if (qbase < N) { qcloud = target;  db = state_x; qoff = qbase;     }
    else           { qcloud = state_x; db = target;  qoff = qbase - N; }

    // Per-thread query coords (divergent VMEM loads, once).
    float mx[QPT], my[QPT], mz[QPT], m[QPT];
    #pragma unroll
    for (int q = 0; q < QPT; ++q) {
        const int j = qoff + q * BLOCK + tid;
        mx[q] = -2.0f * qcloud[3 * j + 0];
        my[q] = -2.0f * qcloud[3 * j + 1];
        mz[q] = -2.0f * qcloud[3 * j + 2];
        m[q] = 3.0e38f;
    }

    const int sliceN = N / SLICES;              // 256
    const int base0 = s * sliceN;

    // Uniform-address loads from const __restrict__ -> s_load (SMEM pipe).
    // b coords stay in SGPRs and feed v_fma as the one legal SGPR operand.
    #pragma unroll 4
    for (int p = 0; p < sliceN; p += 2) {
        const int g = base0 + p;
        const float x0 = db[3 * g + 0], y0 = db[3 * g + 1], z0 = db[3 * g + 2];
        const float x1 = db[3 * g + 3], y1 = db[3 * g + 4], z1 = db[3 * g + 5];
        const float W0 = fmaf(x0, x0, fmaf(y0, y0, z0 * z0));  // VGPR
        const float W1 = fmaf(x1, x1, fmaf(y1, y1, z1 * z1));
        #pragma unroll
        for (int q = 0; q < QPT; ++q) {
            float d0 = fmaf(mx[q], x0, W0);
            d0 = fmaf(my[q], y0, d0);
            d0 = fmaf(mz[q], z0, d0);
            float d1 = fmaf(mx[q], x1, W1);
            d1 = fmaf(my[q], y1, d1);
            d1 = fmaf(mz[q], z1, d1);
            m[q] = fminf(fminf(m[q], d0), d1);   // v_min3_f32
        }
    }

    #pragma unroll
    for (int q = 0; q < QPT; ++q)
        mins[(size_t)s * twoN + qbase + q * BLOCK + tid] = m[q];
}

// 512 blocks x 64 queries. Thread t: query qg+(t&63), slice group t>>6
// (16 slices, latency-parallel loads). Cross-wave min via LDS, sqrt+sum on
// wave 0, block partial + ticket; last block reduces 512 partials -> out.
__global__ __launch_bounds__(BLOCK) void chamfer_finish(
    const float* __restrict__ state_x, const float* __restrict__ target,
    const float* __restrict__ mins, float* __restrict__ partials,
    unsigned* __restrict__ counter, float* __restrict__ out, int N)
{
    const int tid = threadIdx.x;
    const int twoN = 2 * N;
    const int qg = blockIdx.x * 64;
    const int q = qg + (tid & 63);
    const int sgrp = tid >> 6;                  // 0..3 -> slices sgrp*16..+15

    float mv = 3.0e38f;
    #pragma unroll
    for (int k = 0; k < 16; ++k)
        mv = fminf(mv, mins[(size_t)(sgrp * 16 + k) * twoN + q]);

    __shared__ float wmin[4][64];
    wmin[sgrp][tid & 63] = mv;
    __syncthreads();

    float bsum_contrib = 0.0f;
    if (tid < 64) {
        const float mm = fminf(fminf(wmin[0][tid], wmin[1][tid]),
                               fminf(wmin[2][tid], wmin[3][tid]));
        const int qi = qg + tid;
        const float* qc = (qi < N) ? target : state_x;
        const int qx2 = (qi < N) ? qi : qi - N;
        const float ax = qc[3 * qx2 + 0];
        const float ay = qc[3 * qx2 + 1];
        const float az = qc[3 * qx2 + 2];
        const float a2 = fmaf(ax, ax, fmaf(ay, ay, az * az));
        float v = sqrtf(fmaxf(a2 + mm, 0.0f));
        for (int off = 32; off > 0; off >>= 1) v += __shfl_down(v, off, 64);
        bsum_contrib = v;
    }

    __shared__ unsigned is_last;
    if (tid == 0) {
        __hip_atomic_store(&partials[blockIdx.x], bsum_contrib,
                           __ATOMIC_RELEASE, __HIP_MEMORY_SCOPE_AGENT);
        const unsigned old = __hip_atomic_fetch_add(counter, 1u,
                           __ATOMIC_ACQ_REL, __HIP_MEMORY_SCOPE_AGENT);
        is_last = (old == gridDim.x - 1) ? 1u : 0u;
    }
    __syncthreads();

    if (is_last) {   // exactly one block; deterministic fixed-tree sum
        float p = 0.0f;
        for (int i = tid; i < (int)gridDim.x; i += BLOCK)
            p += __hip_atomic_load(&partials[i],
                                   __ATOMIC_ACQUIRE, __HIP_MEMORY_SCOPE_AGENT);
        for (int off = 32; off > 0; off >>= 1) p += __shfl_down(p, off, 64);
        __shared__ float w2[4];
        if ((tid & 63) == 0) w2[tid >> 6] = p;
        __syncthreads();
        if (tid == 0)
            out[0] = (w2[0] + w2[1] + w2[2] + w2[3]) * 5.0f / (float)N;
    }
}

extern "C" void kernel_launch(void* const* d_in, const int* in_sizes, int n_in,
                              void* d_out, int out_size, void* d_ws, size_t ws_size,
                              hipStream_t stream)
{
    const float* state_x = (const float*)d_in[0];
    const float* target  = (const float*)d_in[1];
    float* out = (float*)d_out;

    const int N = in_sizes[0] / 3;               // 16384
    const int twoN = 2 * N;
    const int nFinishBlocks = twoN / 64;         // 512

    float* mins = (float*)d_ws;                  // SLICES*2N floats = 8.4 MB
    float* partials = mins + (size_t)SLICES * twoN;
    unsigned* counter = (unsigned*)(partials + nFinishBlocks);

    const int qchunks = twoN / (BLOCK * QPT);    // 16
    chamfer_partial_min<<<qchunks * SLICES, BLOCK, 0, stream>>>(
        state_x, target, mins, counter, N);
    chamfer_finish<<<nFinishBlocks, BLOCK, 0, stream>>>(
        state_x, target, mins, partials, counter, out, N);
}

// Round 9
// 113.584 us; speedup vs baseline: 1.1224x; 1.1224x over previous
//
#include <hip/hip_runtime.h>
#include <math.h>

// Chamfer loss, two 16384x3 fp32 clouds. Two stream launches.
//
// Ledger (R1-R8): VALU busy floor ~27.7us (scalar == packed fp32 on gfx950,
// 157TF both ways); R8's SGPR-broadcast added VALU (s->v movs, addressing,
// no scalar FP) -> worse. DS b128 broadcast is shared per-CU across the 4
// SIMDs: at QPT=8, DS:VALU issue = ~0.86 -> the 45 vs 28us gap in R3.
//
// R9: LDS-broadcast structure with QPT=16 -> DS pressure halves (ratio
// ~0.43), VALU 3.5 slots/pair (min3 amortized over 2 DB pts) -> ~24us busy.
// SLICES=128: grid = 8 qchunks * 128 = 1024 blocks; __launch_bounds__(256,4)
// caps VGPR at 128 so all 4 blocks/CU are co-resident (16 waves/CU).
// Slice = 128 pts = 2KB staged ONCE, no loop barriers.
//
// Finish: R8's proven ticket/last-block (deterministic single writer),
// 512 blocks, 32 latency-parallel loads/thread over the 16.8MB mins.

#define BLOCK  256
#define QPT    16     // queries per thread
#define SLICES 128    // DB slices; pass-1 grid = 8 * 128 = 1024 blocks

__global__ __launch_bounds__(BLOCK, 4) void chamfer_partial_min(
    const float* __restrict__ state_x, const float* __restrict__ target,
    float* __restrict__ mins, unsigned* __restrict__ counter, int N)
{
    const int tid = threadIdx.x;
    const int twoN = 2 * N;
    const int qchunk = blockIdx.x / SLICES;     // block-uniform
    const int s = blockIdx.x % SLICES;
    const int qbase = qchunk * (BLOCK * QPT);   // 4096-query chunk, 4096 | N

    if (blockIdx.x == 0 && tid == 0) *counter = 0u;   // ticket for pass 2

    const float* qcloud;
    const float* db;
    int qoff;
    if (qbase < N) { qcloud = target;  db = state_x; qoff = qbase;     }
    else           { qcloud = state_x; db = target;  qoff = qbase - N; }

    // Per-thread query coords (once; data is L2-hot).
    float mx[QPT], my[QPT], mz[QPT], m[QPT];
    #pragma unroll
    for (int q = 0; q < QPT; ++q) {
        const int j = qoff + q * BLOCK + tid;
        mx[q] = -2.0f * qcloud[3 * j + 0];
        my[q] = -2.0f * qcloud[3 * j + 1];
        mz[q] = -2.0f * qcloud[3 * j + 2];
        m[q] = 3.0e38f;
    }

    // Stage whole slice once: 128 pts x float4(x,y,z,||b||^2) = 2KB.
    __shared__ float4 tile[16384 / SLICES];
    const int sliceN = N / SLICES;              // 128
    const int base0 = s * sliceN;

    if (tid < sliceN) {
        const int g = base0 + tid;
        const float bx = db[3 * g + 0];
        const float by = db[3 * g + 1];
        const float bz = db[3 * g + 2];
        tile[tid] = make_float4(bx, by, bz,
                                fmaf(bx, bx, fmaf(by, by, bz * bz)));
    }
    __syncthreads();

    // Per 2 DB points: 2 broadcast ds_read_b128 + 16*(6 fma + 1 min3) VALU.
    #pragma unroll 2
    for (int p = 0; p < sliceN; p += 2) {
        const float4 b0 = tile[p + 0];
        const float4 b1 = tile[p + 1];
        #pragma unroll
        for (int q = 0; q < QPT; ++q) {
            float d0 = fmaf(mz[q], b0.z, b0.w);
            d0 = fmaf(my[q], b0.y, d0);
            d0 = fmaf(mx[q], b0.x, d0);
            float d1 = fmaf(mz[q], b1.z, b1.w);
            d1 = fmaf(my[q], b1.y, d1);
            d1 = fmaf(mx[q], b1.x, d1);
            m[q] = fminf(fminf(m[q], d0), d1);   // v_min3_f32
        }
    }

    #pragma unroll
    for (int q = 0; q < QPT; ++q)
        mins[(size_t)s * twoN + qbase + q * BLOCK + tid] = m[q];
}

// 512 blocks x 64 queries. Thread t: query qg+(t&63), slice group t>>6
// (32 slices, latency-parallel loads). Cross-wave min via LDS, sqrt+sum on
// wave 0, block partial + ticket; last block reduces 512 partials -> out.
__global__ __launch_bounds__(BLOCK) void chamfer_finish(
    const float* __restrict__ state_x, const float* __restrict__ target,
    const float* __restrict__ mins, float* __restrict__ partials,
    unsigned* __restrict__ counter, float* __restrict__ out, int N)
{
    const int tid = threadIdx.x;
    const int twoN = 2 * N;
    const int qg = blockIdx.x * 64;
    const int q = qg + (tid & 63);
    const int sgrp = tid >> 6;                  // 0..3 -> slices sgrp*32..+31

    float mv = 3.0e38f;
    #pragma unroll
    for (int k = 0; k < SLICES / 4; ++k)
        mv = fminf(mv, mins[(size_t)(sgrp * (SLICES / 4) + k) * twoN + q]);

    __shared__ float wmin[4][64];
    wmin[sgrp][tid & 63] = mv;
    __syncthreads();

    float bsum_contrib = 0.0f;
    if (tid < 64) {
        const float mm = fminf(fminf(wmin[0][tid], wmin[1][tid]),
                               fminf(wmin[2][tid], wmin[3][tid]));
        const int qi = qg + tid;
        const float* qc = (qi < N) ? target : state_x;
        const int qx2 = (qi < N) ? qi : qi - N;
        const float ax = qc[3 * qx2 + 0];
        const float ay = qc[3 * qx2 + 1];
        const float az = qc[3 * qx2 + 2];
        const float a2 = fmaf(ax, ax, fmaf(ay, ay, az * az));
        float v = sqrtf(fmaxf(a2 + mm, 0.0f));
        for (int off = 32; off > 0; off >>= 1) v += __shfl_down(v, off, 64);
        bsum_contrib = v;
    }

    __shared__ unsigned is_last;
    if (tid == 0) {
        __hip_atomic_store(&partials[blockIdx.x], bsum_contrib,
                           __ATOMIC_RELEASE, __HIP_MEMORY_SCOPE_AGENT);
        const unsigned old = __hip_atomic_fetch_add(counter, 1u,
                           __ATOMIC_ACQ_REL, __HIP_MEMORY_SCOPE_AGENT);
        is_last = (old == gridDim.x - 1) ? 1u : 0u;
    }
    __syncthreads();

    if (is_last) {   // exactly one block; deterministic fixed-tree sum
        float p = 0.0f;
        for (int i = tid; i < (int)gridDim.x; i += BLOCK)
            p += __hip_atomic_load(&partials[i],
                                   __ATOMIC_ACQUIRE, __HIP_MEMORY_SCOPE_AGENT);
        for (int off = 32; off > 0; off >>= 1) p += __shfl_down(p, off, 64);
        __shared__ float w2[4];
        if ((tid & 63) == 0) w2[tid >> 6] = p;
        __syncthreads();
        if (tid == 0)
            out[0] = (w2[0] + w2[1] + w2[2] + w2[3]) * 5.0f / (float)N;
    }
}

extern "C" void kernel_launch(void* const* d_in, const int* in_sizes, int n_in,
                              void* d_out, int out_size, void* d_ws, size_t ws_size,
                              hipStream_t stream)
{
    const float* state_x = (const float*)d_in[0];
    const float* target  = (const float*)d_in[1];
    float* out = (float*)d_out;

    const int N = in_sizes[0] / 3;               // 16384
    const int twoN = 2 * N;
    const int nFinishBlocks = twoN / 64;         // 512

    float* mins = (float*)d_ws;                  // SLICES*2N floats = 16.8 MB
    float* partials = mins + (size_t)SLICES * twoN;
    unsigned* counter = (unsigned*)(partials + nFinishBlocks);

    const int qchunks = twoN / (BLOCK * QPT);    // 8
    chamfer_partial_min<<<qchunks * SLICES, BLOCK, 0, stream>>>(
        state_x, target, mins, counter, N);
    chamfer_finish<<<nFinishBlocks, BLOCK, 0, stream>>>(
        state_x, target, mins, partials, counter, out, N);
}